// Round 9
// baseline (186.833 us; speedup 1.0000x reference)
//
#include <hip/hip_runtime.h>
#include <stdint.h>

// TimeSeriesAttention: x[B,T,C] -> per-head QKV -> causal softmax(QK^T/32) V -> proj
// B=4 T=2048 C=1024 H=16 D=64.
// Device I/O dtype: float32 (reference dtype). Internal compute: bf16 MFMA.
//
// ws layout (elements of bf16):
//   [0,    8M)  x_bf  [B*T][C]
//   [8M,  11M)  wtq   [3072][1024] transposed qkv weights (B^T)
//   [11M, 12M)  wtp   [c][k]       transposed proj weight
//   [12M, 36M)  q,k,v [B*T][H*D]   each 8M elems
//   [28M, 36M)  att   ALIASES v (v dead after transpose_v)
//   [36M, 44M)  vt    [B][H][64][2048]

typedef uint32_t u32;
typedef __bf16 bf16x8 __attribute__((ext_vector_type(8)));
typedef __bf16 bf16x4 __attribute__((ext_vector_type(4)));
typedef unsigned short us8 __attribute__((ext_vector_type(8)));
typedef float f32x4 __attribute__((ext_vector_type(4)));

#define EXP2F(x) __builtin_amdgcn_exp2f(x)

static __device__ __forceinline__ unsigned short f2bf(float f) {
  union { float f; u32 i; } cv; cv.f = f;
  u32 x = cv.i;
  u32 r = (x + 0x7fffu + ((x >> 16) & 1u)) >> 16;  // RNE
  return (unsigned short)r;
}

static __device__ __forceinline__ void gload_lds16(const unsigned short* g, unsigned short* l) {
  __builtin_amdgcn_global_load_lds(
      (__attribute__((address_space(1))) u32*)g,
      (__attribute__((address_space(3))) u32*)l, 16, 0, 0);
}

#define G8_LGKM do { asm volatile("s_waitcnt lgkmcnt(0)" ::: "memory"); \
                     __builtin_amdgcn_sched_barrier(0); } while (0)

// ---------------------------------------------------------------------------
__global__ __launch_bounds__(256) void cvt_f32_bf16(
    const float* __restrict__ src, unsigned short* __restrict__ dst) {
  size_t i = (size_t)(blockIdx.x * 256 + threadIdx.x) * 8u;
  float4 a = *(const float4*)(src + i);
  float4 b = *(const float4*)(src + i + 4);
  us8 v;
  v[0] = f2bf(a.x); v[1] = f2bf(a.y); v[2] = f2bf(a.z); v[3] = f2bf(a.w);
  v[4] = f2bf(b.x); v[5] = f2bf(b.y); v[6] = f2bf(b.z); v[7] = f2bf(b.w);
  *(us8*)(dst + i) = v;
}

// wq/wk/wv [H][C][D] f32 -> wt [n=h*64+d][k=c] bf16
__global__ __launch_bounds__(256) void transpose_qkv(
    const float* __restrict__ wq, const float* __restrict__ wk,
    const float* __restrict__ wv, unsigned short* __restrict__ dst) {
  __shared__ unsigned short lds[64][66];
  const float* src = (blockIdx.z == 0) ? wq : (blockIdx.z == 1) ? wk : wv;
  unsigned short* d = dst + ((size_t)blockIdx.z << 20);
  const int tid = threadIdx.x;
  const int h = blockIdx.y, c0 = blockIdx.x * 64;
  const float* s = src + (size_t)h * 65536u + (size_t)c0 * 64u;
#pragma unroll
  for (int it = 0; it < 16; ++it) {
    int idx = it * 256 + tid;
    int r = idx >> 6, dd = idx & 63;
    lds[dd][r] = f2bf(s[r * 64 + dd]);
  }
  __syncthreads();
#pragma unroll
  for (int it = 0; it < 16; ++it) {
    int idx = it * 256 + tid;
    int dd = idx >> 6, r = idx & 63;
    d[(size_t)(h * 64 + dd) * 1024u + c0 + r] = lds[dd][r];
  }
}

__global__ __launch_bounds__(256) void transpose_proj(
    const float* __restrict__ wp, unsigned short* __restrict__ dst) {
  __shared__ unsigned short lds[64][66];
  const int tid = threadIdx.x;
  const int c0 = blockIdx.x * 64, r0 = blockIdx.y * 64;
#pragma unroll
  for (int it = 0; it < 16; ++it) {
    int idx = it * 256 + tid;
    int r = idx >> 6, cc = idx & 63;
    lds[cc][r] = f2bf(wp[(size_t)(r0 + r) * 1024u + c0 + cc]);
  }
  __syncthreads();
#pragma unroll
  for (int it = 0; it < 16; ++it) {
    int idx = it * 256 + tid;
    int cc = idx >> 6, r = idx & 63;
    dst[(size_t)(c0 + cc) * 1024u + r0 + r] = lds[cc][r];
  }
}

__global__ __launch_bounds__(256) void transpose_v(
    const unsigned short* __restrict__ v, unsigned short* __restrict__ vt) {
  __shared__ unsigned short lds[64][66];
  const int tid = threadIdx.x;
  const int bh = blockIdx.y, t0 = blockIdx.x * 64;
  const unsigned short* src = v + ((size_t)(bh >> 4) * 2048 + t0) * 1024u + (bh & 15) * 64;
  unsigned short* dst = vt + (size_t)bh * 131072u + t0;
#pragma unroll
  for (int it = 0; it < 16; ++it) {
    int idx = it * 256 + tid;
    int r = idx >> 6, dd = idx & 63;
    lds[dd][r] = src[(size_t)r * 1024u + dd];
  }
  __syncthreads();
#pragma unroll
  for (int it = 0; it < 16; ++it) {
    int idx = it * 256 + tid;
    int dd = idx >> 6, r = idx & 63;
    dst[(size_t)dd * 2048u + r] = lds[dd][r];
  }
}

// ---------------------------------------------------------------------------
// 128x256 4-phase BT-GEMM (T1..T5). K=1024, BK=64 (16 K-tiles, 8 iters x 2).
// 8 waves 2Mx4N, per-wave 64x64 (acc[4][4]). LDS 96KB: A[2][128*64] bf16 +
// B[2][256*64] bf16, chunk-XOR swizzle c^=(row&7) (pre-swizzled global src,
// swizzled ds_read). Per iter: p0/p1 = tile 2j (slot0, B np0/np1),
// p2/p3 = tile 2j+1 (slot1). Stages: p0:B(2j+1)h0h1->s1, p1:A(2j+2)->s0,
// p2:B(2j+2)->s0, p3:A(2j+3)->s1. vmcnt(2) at p1/p3 end (counted, never 0
// mid-loop). Grid: 64 mt x NXT nt; mt=(bid&7)*8+((bid>>3)&7), nt=bid>>6 ->
// same-XCD blocks share 8 A-tiles (2MB L2-resident) and stream B nt-major.
static __device__ __forceinline__ void gn_stage(const unsigned short* g,
                                                unsigned short* d, int tid) {
#pragma unroll
  for (int l = 0; l < 2; ++l) {
    int cid = l * 512 + tid;          // 1024 chunks of 16B (128 rows x 8)
    int r = cid >> 3, c = cid & 7;
    gload_lds16(g + (size_t)r * 1024 + ((c ^ (r & 7)) << 3), d + cid * 8);
  }
}
static __device__ __forceinline__ void gn_ldA(bf16x8 af[4][2], const unsigned short* As,
                                              int wr, int l15, int lhi) {
#pragma unroll
  for (int mi = 0; mi < 4; ++mi)
#pragma unroll
    for (int ks = 0; ks < 2; ++ks) {
      int row = wr * 64 + mi * 16 + l15;
      af[mi][ks] = *(const bf16x8*)(As + row * 64 + ((((ks << 2) | lhi) ^ (row & 7)) << 3));
    }
}
static __device__ __forceinline__ void gn_ldB(bf16x8 bf[2][2], const unsigned short* Bs,
                                              int wc, int np, int l15, int lhi) {
#pragma unroll
  for (int ni = 0; ni < 2; ++ni)
#pragma unroll
    for (int ks = 0; ks < 2; ++ks) {
      int row = wc * 64 + np * 32 + ni * 16 + l15;
      bf[ni][ks] = *(const bf16x8*)(Bs + row * 64 + ((((ks << 2) | lhi) ^ (row & 7)) << 3));
    }
}
static __device__ __forceinline__ void gn_quad(f32x4 acc[4][4], bf16x8 af[4][2],
                                               bf16x8 bf[2][2], int np) {
#pragma unroll
  for (int ks = 0; ks < 2; ++ks)
#pragma unroll
    for (int mi = 0; mi < 4; ++mi)
#pragma unroll
      for (int ni = 0; ni < 2; ++ni)
        acc[mi][np * 2 + ni] = __builtin_amdgcn_mfma_f32_16x16x32_bf16(
            af[mi][ks], bf[ni][ks], acc[mi][np * 2 + ni], 0, 0, 0);
}

template <int F32OUT>
__global__ __launch_bounds__(512, 2) void gemmN(
    const unsigned short* __restrict__ A, const unsigned short* __restrict__ Bt,
    const float* __restrict__ bias, void* __restrict__ Cv) {
  extern __shared__ __align__(16) unsigned short ldsm[];
  unsigned short* Ab = ldsm;          // slots at +0 / +8192
  unsigned short* Bb = ldsm + 16384;  // slots at +0 / +16384
  const int tid = threadIdx.x, wid = tid >> 6, lane = tid & 63;
  const int l15 = lane & 15, lhi = lane >> 4;
  const int wr = wid >> 2, wc = wid & 3;
  const int bid = blockIdx.x;
  const int mt = ((bid & 7) << 3) | ((bid >> 3) & 7);
  const int nt = bid >> 6;
  const int m0 = mt * 128, n0 = nt * 256;
  const unsigned short* Ag = A + (size_t)m0 * 1024;
  const unsigned short* Bg = Bt + (size_t)n0 * 1024;

  f32x4 acc[4][4] = {};
  bf16x8 af[4][2], b0[2][2], b1[2][2];

  // prologue: B(0) h0+h1 -> Bs0, A(0) -> As0, A(64) -> As1
  gn_stage(Bg, Bb, tid);
  gn_stage(Bg + 128 * 1024, Bb + 8192, tid);
  gn_stage(Ag, Ab, tid);
  gn_stage(Ag + 64, Ab + 8192, tid);
  asm volatile("s_waitcnt vmcnt(2)" ::: "memory");
  __builtin_amdgcn_s_barrier();

  for (int j = 0; j < 8; ++j) {
    const bool last = (j == 7);
    const int kc = j * 128;
    // p0: tile 2j, B np0; stage B(2j+1) -> Bs1
    gn_ldA(af, Ab, wr, l15, lhi);
    gn_ldB(b0, Bb, wc, 0, l15, lhi);
    gn_stage(Bg + (kc + 64), Bb + 16384, tid);
    gn_stage(Bg + 128 * 1024 + (kc + 64), Bb + 24576, tid);
    __builtin_amdgcn_s_barrier(); G8_LGKM;
    __builtin_amdgcn_s_setprio(1); gn_quad(acc, af, b0, 0); __builtin_amdgcn_s_setprio(0);
    __builtin_amdgcn_s_barrier();
    // p1: B np1; stage A(2j+2) -> As0
    gn_ldB(b1, Bb, wc, 1, l15, lhi);
    if (!last) gn_stage(Ag + (kc + 128), Ab, tid);
    __builtin_amdgcn_s_barrier(); G8_LGKM;
    __builtin_amdgcn_s_setprio(1); gn_quad(acc, af, b1, 1); __builtin_amdgcn_s_setprio(0);
    if (last) { asm volatile("s_waitcnt vmcnt(0)" ::: "memory"); }
    else      { asm volatile("s_waitcnt vmcnt(2)" ::: "memory"); }
    __builtin_amdgcn_s_barrier();
    // p2: tile 2j+1, B np0; stage B(2j+2) -> Bs0
    gn_ldA(af, Ab + 8192, wr, l15, lhi);
    gn_ldB(b0, Bb + 16384, wc, 0, l15, lhi);
    if (!last) {
      gn_stage(Bg + (kc + 128), Bb, tid);
      gn_stage(Bg + 128 * 1024 + (kc + 128), Bb + 8192, tid);
    }
    __builtin_amdgcn_s_barrier(); G8_LGKM;
    __builtin_amdgcn_s_setprio(1); gn_quad(acc, af, b0, 0); __builtin_amdgcn_s_setprio(0);
    __builtin_amdgcn_s_barrier();
    // p3: B np1; stage A(2j+3) -> As1
    gn_ldB(b1, Bb + 16384, wc, 1, l15, lhi);
    if (!last) gn_stage(Ag + (kc + 192), Ab + 8192, tid);
    __builtin_amdgcn_s_barrier(); G8_LGKM;
    __builtin_amdgcn_s_setprio(1); gn_quad(acc, af, b1, 1); __builtin_amdgcn_s_setprio(0);
    if (!last) asm volatile("s_waitcnt vmcnt(2)" ::: "memory");
    __builtin_amdgcn_s_barrier();
  }

#pragma unroll
  for (int mi = 0; mi < 4; ++mi) {
#pragma unroll
    for (int ni = 0; ni < 4; ++ni) {
      const int n = n0 + wc * 64 + ni * 16 + l15;
      const int mr = m0 + wr * 64 + mi * 16 + lhi * 4;
      if constexpr (F32OUT) {
        float* O = (float*)Cv;
        const float b = bias[n];
#pragma unroll
        for (int r = 0; r < 4; ++r)
          O[(size_t)(mr + r) * 1024 + n] = acc[mi][ni][r] + b;
      } else {
        unsigned short* O = (unsigned short*)Cv + ((size_t)(n >> 10) << 23);
        const int nc = n & 1023;
#pragma unroll
        for (int r = 0; r < 4; ++r)
          O[(size_t)(mr + r) * 1024 + nc] = f2bf(acc[mi][ni][r]);
      }
    }
  }
}

// ---------------------------------------------------------------------------
// Flash causal attention, swapped-operand softmax, 8 waves x 16 q-rows.
// Grid 768 (1-D): xcd = bid&7 owns bh in [xcd*8, xcd*8+8) -> per-XCD KV
// working set = 8 x 512KB = 4MB = L2. part = bid>>6 selects a q-tile set
// from QPART (12 parts/bh, weights 2..32 KV-tiles, 3 blocks/CU resident).
#define QT 128
#define KVT 64
#define PSTR 72
#define SCLOG2E 0.04508422f  // (1/32) * log2(e)
#define DTHR 128.0f

__device__ const unsigned short QPART[12] = {
    0x8000, 0x4000, 0x2000, 0x1000, 0x0800, 0x0400,
    0x0200, 0x0102, 0x0084, 0x0048, 0x0030, 0x0001};

__global__ __launch_bounds__(512, 4) void attn_fwd(
    const unsigned short* __restrict__ Qg, const unsigned short* __restrict__ Kg,
    const unsigned short* __restrict__ Vtg, unsigned short* __restrict__ Og) {
  __shared__ __align__(16) unsigned short Kl[2][64 * 64];
  __shared__ __align__(16) unsigned short Vl[2][64 * 64];
  __shared__ __align__(16) unsigned short Pl[8][16 * PSTR];
  const int tid = threadIdx.x, wid = tid >> 6, lane = tid & 63;
  const int l15 = lane & 15, lhi = lane >> 4, x7 = lane & 7;
  const int bid = blockIdx.x;
  const int bh = ((bid & 7) << 3) | ((bid >> 3) & 7);
  const int part = bid >> 6;
  const unsigned qm = QPART[part];
  const int qt0 = __builtin_ctz(qm);
  const int qt1 = 31 - __builtin_clz(qm);
  const int npass = (qt0 == qt1) ? 1 : 2;
  const int n0 = 2 * (qt0 + 1), n1 = 2 * (qt1 + 1);
  const int ntot = (npass == 2) ? (n0 + n1) : n0;
  const size_t base = (size_t)(bh >> 4) * (2048u * 1024u) + (size_t)(bh & 15) * 64u;
  const size_t vtbase = (size_t)bh * (64u * 2048u);

  auto s0_of = [&](int g) { return ((g < n0) ? g : g - n0) * KVT; };

  auto stage = [&](int bufi, int s0) {
    int q = tid;
    int r = q >> 3;
    int c = (q & 7) ^ (r & 7);
    gload_lds16(Kg + base + (size_t)(s0 + r) * 1024u + c * 8, &Kl[bufi][q * 8]);
    gload_lds16(Vtg + vtbase + (size_t)r * 2048u + s0 + c * 8, &Vl[bufi][q * 8]);
  };

  stage(0, 0);
  __syncthreads();

  int g = 0;
  for (int pass = 0; pass < npass; ++pass) {
    const int qt = pass ? qt1 : qt0;
    const int nt = pass ? n1 : n0;
    const int qrow0 = qt * QT + wid * 16;

    bf16x8 qf[2];
#pragma unroll
    for (int kj = 0; kj < 2; ++kj)
      qf[kj] = *(const bf16x8*)(Qg + base +
          (size_t)(qrow0 + l15) * 1024u + kj * 32 + lhi * 8);

    float mrun = -1e30f, lrun = 0.0f;
    f32x4 oacc[4] = {};

    for (int kt = 0; kt < nt; ++kt, ++g) {
      const int cur = g & 1;
      const int s0 = kt * KVT;
      if (g + 1 < ntot) stage(cur ^ 1, s0_of(g + 1));
      if (s0 <= qrow0 + 15) {
        const bool notfull = (s0 + KVT - 1 > qrow0);
        const unsigned short* Kb = Kl[cur];
        const unsigned short* Vb = Vl[cur];

        f32x4 sacc[4] = {};
#pragma unroll
        for (int kj = 0; kj < 2; ++kj) {
          bf16x8 kf[4];
#pragma unroll
          for (int sj = 0; sj < 4; ++sj) {
            int r = sj * 16 + l15;
            kf[sj] = *(const bf16x8*)(&Kb[r * 64 + (((kj * 4 + lhi) ^ x7) * 8)]);
          }
#pragma unroll
          for (int sj = 0; sj < 4; ++sj)
            sacc[sj] = __builtin_amdgcn_mfma_f32_16x16x32_bf16(
                kf[sj], qf[kj], sacc[sj], 0, 0, 0);
        }

        const int qa = qrow0 + l15;
        float mx = -3e38f;
        if (notfull) {
#pragma unroll
          for (int sj = 0; sj < 4; ++sj)
#pragma unroll
            for (int r = 0; r < 4; ++r) {
              int sa = s0 + sj * 16 + lhi * 4 + r;
              float v = (sa <= qa) ? sacc[sj][r] : -3e38f;
              sacc[sj][r] = v;
              mx = fmaxf(mx, v);
            }
        } else {
#pragma unroll
          for (int sj = 0; sj < 4; ++sj)
#pragma unroll
            for (int r = 0; r < 4; ++r)
              mx = fmaxf(mx, sacc[sj][r]);
        }
        mx = fmaxf(mx, __shfl_xor(mx, 16, 64));
        mx = fmaxf(mx, __shfl_xor(mx, 32, 64));

        if (__any(mx > mrun + DTHR)) {
          float mnew = fmaxf(mrun, mx);
          float sc = EXP2F((mrun - mnew) * SCLOG2E);
          mrun = mnew;
          lrun *= sc;
#pragma unroll
          for (int r = 0; r < 4; ++r) {
            float so = __shfl(sc, (lane & 48) + lhi * 4 + r, 64);
#pragma unroll
            for (int dj = 0; dj < 4; ++dj) oacc[dj][r] *= so;
          }
        }

        {
          const float m = mrun;
          float ps = 0.0f;
#pragma unroll
          for (int sj = 0; sj < 4; ++sj) {
            float p0 = EXP2F((sacc[sj][0] - m) * SCLOG2E);
            float p1 = EXP2F((sacc[sj][1] - m) * SCLOG2E);
            float p2 = EXP2F((sacc[sj][2] - m) * SCLOG2E);
            float p3 = EXP2F((sacc[sj][3] - m) * SCLOG2E);
            bf16x4 pk;
            pk[0] = (__bf16)p0; pk[1] = (__bf16)p1;
            pk[2] = (__bf16)p2; pk[3] = (__bf16)p3;
            *(bf16x4*)(&Pl[wid][l15 * PSTR + sj * 16 + lhi * 4]) = pk;
            ps += (p0 + p1) + (p2 + p3);
          }
          ps += __shfl_xor(ps, 16, 64);
          ps += __shfl_xor(ps, 32, 64);
          lrun += ps;
        }

#pragma unroll
        for (int kk = 0; kk < 2; ++kk) {
          bf16x8 pf, vf[4];
          pf = *(const bf16x8*)(&Pl[wid][l15 * PSTR + kk * 32 + lhi * 8]);
#pragma unroll
          for (int dj = 0; dj < 4; ++dj) {
            int r = dj * 16 + l15;
            vf[dj] = *(const bf16x8*)(&Vb[r * 64 + (((kk * 4 + lhi) ^ x7) * 8)]);
          }
#pragma unroll
          for (int dj = 0; dj < 4; ++dj)
            oacc[dj] = __builtin_amdgcn_mfma_f32_16x16x32_bf16(
                pf, vf[dj], oacc[dj], 0, 0, 0);
        }
      }

      __syncthreads();
    }

    float rn[4];
#pragma unroll
    for (int r = 0; r < 4; ++r)
      rn[r] = 1.0f / __shfl(lrun, (lane & 48) + lhi * 4 + r, 64);
#pragma unroll
    for (int dj = 0; dj < 4; ++dj)
#pragma unroll
      for (int r = 0; r < 4; ++r) {
        int t = qrow0 + lhi * 4 + r;
        Og[base + (size_t)t * 1024u + dj * 16 + l15] = f2bf(oacc[dj][r] * rn[r]);
      }
  }
}

// ---------------------------------------------------------------------------
extern "C" void kernel_launch(void* const* d_in, const int* in_sizes, int n_in,
                              void* d_out, int out_size, void* d_ws, size_t ws_size,
                              hipStream_t stream) {
  const float* x  = (const float*)d_in[0];
  const float* wq = (const float*)d_in[1];
  const float* wk = (const float*)d_in[2];
  const float* wv = (const float*)d_in[3];
  const float* wp = (const float*)d_in[4];
  const float* bp = (const float*)d_in[5];
  float* out = (float*)d_out;

  unsigned short* ws   = (unsigned short*)d_ws;
  unsigned short* x_bf = ws;                          // 8M elems
  unsigned short* wtq  = ws + ((size_t)8 << 20);      // 3M ([3072][1024] B^T)
  unsigned short* wtp  = ws + ((size_t)11 << 20);     // 1M
  unsigned short* qkv  = ws + ((size_t)12 << 20);     // 24M (q,k,v @ 8M stride)
  unsigned short* q    = qkv;
  unsigned short* kk   = qkv + ((size_t)8 << 20);
  unsigned short* vv   = qkv + ((size_t)16 << 20);
  unsigned short* att  = vv;                          // alias: v dead after transpose_v
  unsigned short* vt   = ws + ((size_t)36 << 20);     // 8M

  (void)hipFuncSetAttribute(reinterpret_cast<const void*>(&gemmN<0>),
                            hipFuncAttributeMaxDynamicSharedMemorySize, 98304);
  (void)hipFuncSetAttribute(reinterpret_cast<const void*>(&gemmN<1>),
                            hipFuncAttributeMaxDynamicSharedMemorySize, 98304);

  cvt_f32_bf16<<<4096, 256, 0, stream>>>(x, x_bf);
  transpose_qkv<<<dim3(16, 16, 3), 256, 0, stream>>>(wq, wk, wv, wtq);
  transpose_proj<<<dim3(16, 16), 256, 0, stream>>>(wp, wtp);
  // merged QKV projection: M=8192, N=3072 -> 64x12 = 768 blocks (3 exact waves)
  gemmN<0><<<768, 512, 98304, stream>>>(x_bf, wtq, nullptr, qkv);
  transpose_v<<<dim3(32, 64), 256, 0, stream>>>(vv, vt);
  attn_fwd<<<768, 512, 0, stream>>>(q, kk, vt, att);
  // output projection: M=8192, N=1024 -> 64x4 = 256 blocks (1 exact wave)
  gemmN<1><<<256, 512, 98304, stream>>>(att, wtp, bp, out);
}